// Round 5
// baseline (464.922 us; speedup 1.0000x reference)
//
#include <hip/hip_runtime.h>
#include <hip/hip_bf16.h>

// Head-axis-softmax SDPA, B=2 S=2048 N=16 D=64, fp32 in/out.
// softmax over HEADS (n) -> local per (b,q,k).
//
// R5: fully barrier-free two-pass.
//  - den_kernel: ONE WAVE computes QK scores for ALL 16 heads of a 32x32
//    (q,k) tile; all heads share the same MFMA C lane-mapping, so the
//    cross-head sum is pure per-lane register math (no LDS/atomics/barriers).
//    Writes rd = mask ? 1/sum_n exp(s_n/8) : NaN as bf16 (per batch, 8.4 MB).
//  - apply_kernel: per-head, 4 independent waves/block, no barrier in k-loop;
//    recomputes s with the IDENTICAL mfma chunk sequence (bitwise-same s),
//    w = exp(s)*rd, wave-local LDS C->A transform, LDS epilogue, direct store.
//  ws = [Qb 8MB][Kb 8MB][Vt 8MB][RD 8.4MB] = 32.4 MB (proven floor: >=33.5).
//  Batches sequential so RD can be single-batch.

#define B_ 2
#define S_ 2048
#define N_ 16
#define D_ 64
#define PK 40

typedef __bf16 bf16x4 __attribute__((ext_vector_type(4)));
typedef __bf16 bf16x8 __attribute__((ext_vector_type(8)));
typedef float  f32x16 __attribute__((ext_vector_type(16)));

// ---------------------------------------------------------------------------
// Pre-pass 1: Q,K [b,s,n,d] f32 -> [b,n,s,d] bf16. Both sides coalesced.
// ---------------------------------------------------------------------------
__global__ __launch_bounds__(256) void cvt_qk_kernel(
    const float* __restrict__ Qf, const float* __restrict__ Kf,
    __bf16* __restrict__ Qb, __bf16* __restrict__ Kb)
{
    const int z = blockIdx.z;                  // 0..2B-1: first B -> Q, rest -> K
    const float* src = (z < B_) ? Qf : Kf;
    __bf16*      dst = (z < B_) ? Qb : Kb;
    const int b = (z < B_) ? z : z - B_;
    const int n = blockIdx.y;
    const int t = threadIdx.x;
    const int d4 = (t & 15) * 4;
    const int s  = blockIdx.x * 16 + (t >> 4);

    const float4 v = *(const float4*)&src[(((size_t)b * S_ + s) * N_ + n) * D_ + d4];
    bf16x4 o;
    o[0] = (__bf16)v.x; o[1] = (__bf16)v.y; o[2] = (__bf16)v.z; o[3] = (__bf16)v.w;
    *(bf16x4*)&dst[(((size_t)b * N_ + n) * S_ + s) * D_ + d4] = o;
}

// ---------------------------------------------------------------------------
// Pre-pass 2: V [b,s,n,d] f32 -> [b,n,d,s] bf16 (d<->s transpose via LDS).
// ---------------------------------------------------------------------------
__global__ __launch_bounds__(256) void cvt_v_kernel(
    const float* __restrict__ V, __bf16* __restrict__ Vt)
{
    __shared__ __bf16 tile[64][68];
    const int s0 = blockIdx.x * 64;
    const int n  = blockIdx.y;
    const int b  = blockIdx.z;
    const int t  = threadIdx.x;

    {
        const int d4 = (t & 15) * 4;
        const int sr = t >> 4;
        #pragma unroll
        for (int r = 0; r < 4; ++r) {
            const int s = sr + r * 16;
            const float4 v = *(const float4*)&V[(((size_t)b * S_ + s0 + s) * N_ + n) * D_ + d4];
            tile[s][d4 + 0] = (__bf16)v.x;
            tile[s][d4 + 1] = (__bf16)v.y;
            tile[s][d4 + 2] = (__bf16)v.z;
            tile[s][d4 + 3] = (__bf16)v.w;
        }
    }
    __syncthreads();
    {
        const int s4 = (t & 15) * 4;
        const int dr = t >> 4;
        #pragma unroll
        for (int r = 0; r < 4; ++r) {
            const int d = dr + r * 16;
            bf16x4 o;
            o[0] = tile[s4 + 0][d];
            o[1] = tile[s4 + 1][d];
            o[2] = tile[s4 + 2][d];
            o[3] = tile[s4 + 3][d];
            *(bf16x4*)&Vt[(((size_t)b * N_ + n) * D_ + d) * S_ + s0 + s4] = o;
        }
    }
}

// ---------------------------------------------------------------------------
// den v2: wave = one 32x32 (q,k) tile, all 16 heads in registers.
// Block 256 = 4 waves on consecutive k-subtiles. NO LDS, NO barriers.
// grid (S/128, S/32, 1); batch is a kernel arg (RD reused across batches).
// ---------------------------------------------------------------------------
__global__ __launch_bounds__(256) void den_kernel(
    const __bf16* __restrict__ Qb, const __bf16* __restrict__ Kb,
    const int* __restrict__ M, __bf16* __restrict__ RD, int b)
{
    const int tid  = threadIdx.x;
    const int w    = tid >> 6;
    const int lane = tid & 63;
    const int lo   = lane & 31;
    const int hi   = lane >> 5;

    const int q0 = blockIdx.y * 32;
    const int k0 = blockIdx.x * 128 + w * 32;

    const __bf16* Qp = Qb + (size_t)b * N_ * S_ * D_ + (size_t)(q0 + lo) * D_ + hi * 8;
    const __bf16* Kp = Kb + (size_t)b * N_ * S_ * D_ + (size_t)(k0 + lo) * D_ + hi * 8;

    f32x16 sum = {};
    for (int n = 0; n < N_; ++n) {
        const __bf16* qh = Qp + (size_t)n * S_ * D_;
        const __bf16* kh = Kp + (size_t)n * S_ * D_;
        f32x16 acc = {};
        #pragma unroll
        for (int c = 0; c < 4; ++c) {
            bf16x8 qf = *(const bf16x8*)(qh + c * 16);
            bf16x8 kf = *(const bf16x8*)(kh + c * 16);
            acc = __builtin_amdgcn_mfma_f32_32x32x16_bf16(qf, kf, acc, 0, 0, 0);
        }
        #pragma unroll
        for (int r = 0; r < 16; ++r) sum[r] += __expf(acc[r] * 0.125f);
    }

    // rd = mask ? 1/sum : NaN  (mask uniform over heads), bf16 store
    #pragma unroll
    for (int r = 0; r < 16; ++r) {
        const int row = (r & 3) + 8 * (r >> 2) + 4 * hi;   // C layout
        const int m = M[(size_t)b * S_ * S_ + (size_t)(q0 + row) * S_ + (k0 + lo)];
        const float rd = m ? (1.0f / sum[r]) : __builtin_nanf("");
        RD[(size_t)(q0 + row) * S_ + (k0 + lo)] = (__bf16)rd;
    }
}

// ---------------------------------------------------------------------------
// apply v2: block = 4 waves, one head; wave w owns k-strip [w*512, w*512+512).
// No barriers in the k-loop; s recomputed with the same chunk sequence as den.
// Epilogue: LDS 4-way reduce + direct coalesced store (no global atomics).
// grid (S/32, N, 1); batch is a kernel arg.
// ---------------------------------------------------------------------------
__global__ __launch_bounds__(256) void apply_kernel(
    const __bf16* __restrict__ Qb, const __bf16* __restrict__ Kb,
    const __bf16* __restrict__ Vt, const __bf16* __restrict__ RD,
    float* __restrict__ O, int b)
{
    __shared__ __align__(16) __bf16 pw[4][32][PK];  // per-wave w tiles, 10 KB
    __shared__ float obuf[32][64];                   // 8 KB

    const int tid  = threadIdx.x;
    const int w    = tid >> 6;
    const int lane = tid & 63;
    const int lo   = lane & 31;
    const int hi   = lane >> 5;

    const int q0 = blockIdx.x * 32;
    const int n  = blockIdx.y;

    float* obf = &obuf[0][0];
    #pragma unroll
    for (int i = 0; i < 8; ++i) obf[i * 256 + tid] = 0.0f;
    __syncthreads();  // obuf zeroed before any wave's epilogue atomics

    const __bf16* Qh = Qb + ((size_t)b * N_ + n) * S_ * D_;
    const __bf16* Kh = Kb + ((size_t)b * N_ + n) * S_ * D_;
    const __bf16* Vh = Vt + ((size_t)b * N_ + n) * D_ * S_;

    // Q A-frags (persistent): A[m=lo][k = c*16 + hi*8 + j]
    bf16x8 qf[4];
    #pragma unroll
    for (int c = 0; c < 4; ++c)
        qf[c] = *(const bf16x8*)&Qh[(size_t)(q0 + lo) * D_ + c * 16 + hi * 8];

    f32x16 o0 = {};
    f32x16 o1 = {};

    for (int it = 0; it < 16; ++it) {
        const int k0 = w * 512 + it * 32;

        // QK^T: same 4-chunk 32x32x16 sequence as den -> bitwise-identical s
        f32x16 s = {};
        #pragma unroll
        for (int c = 0; c < 4; ++c) {
            bf16x8 kf = *(const bf16x8*)&Kh[(size_t)(k0 + lo) * D_ + c * 16 + hi * 8];
            s = __builtin_amdgcn_mfma_f32_32x32x16_bf16(qf[c], kf, s, 0, 0, 0);
        }

        // V B-frags, issued early (latency overlaps exp/rd/LDS below)
        bf16x8 vf[2][2];
        #pragma unroll
        for (int ks = 0; ks < 2; ++ks)
            #pragma unroll
            for (int dt = 0; dt < 2; ++dt)
                vf[ks][dt] = *(const bf16x8*)&Vh[(size_t)(dt * 32 + lo) * S_
                                                 + k0 + ks * 16 + hi * 8];

        // w = exp(s/8) * rd -> wave-local LDS (C-layout scatter)
        #pragma unroll
        for (int r = 0; r < 16; ++r) {
            const int row = (r & 3) + 8 * (r >> 2) + 4 * hi;
            const float rd = (float)RD[(size_t)(q0 + row) * S_ + (k0 + lo)];
            pw[w][row][lo] = (__bf16)(__expf(s[r] * 0.125f) * rd);
        }

        // wave-local C->A transform read (compiler inserts lgkmcnt; no barrier)
        #pragma unroll
        for (int ks = 0; ks < 2; ++ks) {
            bf16x8 wf = *(const bf16x8*)&pw[w][lo][ks * 16 + hi * 8];
            o0 = __builtin_amdgcn_mfma_f32_32x32x16_bf16(wf, vf[ks][0], o0, 0, 0, 0);
            o1 = __builtin_amdgcn_mfma_f32_32x32x16_bf16(wf, vf[ks][1], o1, 0, 0, 0);
        }
    }

    // 4-way k-strip reduce in LDS
    #pragma unroll
    for (int r = 0; r < 16; ++r) {
        const int row = (r & 3) + 8 * (r >> 2) + 4 * hi;
        atomicAdd(&obuf[row][lo],      o0[r]);
        atomicAdd(&obuf[row][32 + lo], o1[r]);
    }
    __syncthreads();

    // direct coalesced store — every output element written exactly once
    #pragma unroll
    for (int i = 0; i < 8; ++i) {
        const int c = i * 256 + tid;
        const int q = c >> 6, d = c & 63;
        O[(((size_t)b * N_ + n) * S_ + (q0 + q)) * D_ + d] = obuf[q][d];
    }
}

// ---------------------------------------------------------------------------
// Fallback: R4 main kernel (monolithic, repacked inputs). Needs 24 MB ws.
// ---------------------------------------------------------------------------
#define TQ 32
#define TK 32
#define KSPLIT 4
#define ITERS (S_ / TK / KSPLIT)

__global__ __launch_bounds__(1024) void sdpa_main_kernel(
    const __bf16* __restrict__ Qb, const __bf16* __restrict__ Kb,
    const __bf16* __restrict__ Vt, const int* __restrict__ M,
    float* __restrict__ O)
{
    __shared__ __align__(16) __bf16 pbuf[N_][TQ][PK];

    const int tid  = threadIdx.x;
    const int n    = tid >> 6;
    const int lane = tid & 63;
    const int lo   = lane & 31;
    const int hi   = lane >> 5;

    const int q0 = blockIdx.x * TQ;
    const int b  = blockIdx.y;
    const int kz = blockIdx.z;

    const __bf16* Qh = Qb + ((size_t)b * N_ + n) * S_ * D_;
    const __bf16* Kh = Kb + ((size_t)b * N_ + n) * S_ * D_;
    const __bf16* Vh = Vt + ((size_t)b * N_ + n) * D_ * S_;

    bf16x8 qf[4];
    #pragma unroll
    for (int ks = 0; ks < 4; ++ks)
        qf[ks] = *(const bf16x8*)&Qh[(size_t)(q0 + lo) * D_ + ks * 16 + hi * 8];

    f32x16 o0 = {};
    f32x16 o1 = {};

    for (int it = 0; it < ITERS; ++it) {
        const int k0 = (kz * ITERS + it) * TK;

        f32x16 s = {};
        #pragma unroll
        for (int ks = 0; ks < 4; ++ks) {
            bf16x8 kf = *(const bf16x8*)&Kh[(size_t)(k0 + lo) * D_ + ks * 16 + hi * 8];
            s = __builtin_amdgcn_mfma_f32_32x32x16_bf16(qf[ks], kf, s, 0, 0, 0);
        }

        bf16x8 vf[2][2];
        #pragma unroll
        for (int kstep = 0; kstep < 2; ++kstep)
            #pragma unroll
            for (int dt = 0; dt < 2; ++dt)
                vf[kstep][dt] = *(const bf16x8*)&Vh[(size_t)(dt * 32 + lo) * S_
                                                   + k0 + kstep * 16 + hi * 8];

        #pragma unroll
        for (int r = 0; r < 16; ++r) {
            const int row = (r & 3) + 8 * (r >> 2) + 4 * hi;
            pbuf[n][row][lo] = (__bf16)__expf(s[r] * 0.125f);
        }

        __syncthreads();

        {
            const int tq = tid >> 5;
            const int tk = tid & 31;
            const int m = M[(size_t)b * S_ * S_ + (size_t)(q0 + tq) * S_ + (k0 + tk)];
            float pv[16];
            float sum = 0.f;
            #pragma unroll
            for (int j = 0; j < 16; ++j) { pv[j] = (float)pbuf[j][tq][tk]; sum += pv[j]; }
            const float rd = m ? (1.0f / sum) : __builtin_nanf("");
            #pragma unroll
            for (int j = 0; j < 16; ++j) pbuf[j][tq][tk] = (__bf16)(pv[j] * rd);
        }

        __syncthreads();

        #pragma unroll
        for (int kstep = 0; kstep < 2; ++kstep) {
            bf16x8 wf = *(const bf16x8*)&pbuf[n][lo][kstep * 16 + hi * 8];
            o0 = __builtin_amdgcn_mfma_f32_32x32x16_bf16(wf, vf[kstep][0], o0, 0, 0, 0);
            o1 = __builtin_amdgcn_mfma_f32_32x32x16_bf16(wf, vf[kstep][1], o1, 0, 0, 0);
        }

        __syncthreads();
    }

    #pragma unroll
    for (int r = 0; r < 16; ++r) {
        const int row = (r & 3) + 8 * (r >> 2) + 4 * hi;
        const size_t base = (((size_t)b * N_ + n) * S_ + (q0 + row)) * (size_t)D_;
        atomicAdd(&O[base + lo],      o0[r]);
        atomicAdd(&O[base + 32 + lo], o1[r]);
    }
}

extern "C" void kernel_launch(void* const* d_in, const int* in_sizes, int n_in,
                              void* d_out, int out_size, void* d_ws, size_t ws_size,
                              hipStream_t stream) {
    const float* Q = (const float*)d_in[0];
    const float* K = (const float*)d_in[1];
    const float* V = (const float*)d_in[2];
    const int*   M = (const int*)d_in[3];
    float* O = (float*)d_out;

    const size_t per  = (size_t)B_ * N_ * S_ * D_;               // 4.19 M elems
    const size_t rdel = (size_t)S_ * S_;                         // 4.19 M elems (1 batch)
    const size_t need_new = (3 * per + rdel) * sizeof(__bf16);   // 32.5 MB

    if (ws_size >= need_new) {
        __bf16* Qb = (__bf16*)d_ws;
        __bf16* Kb = Qb + per;
        __bf16* Vt = Kb + per;
        __bf16* RD = Vt + per;
        cvt_qk_kernel<<<dim3(S_ / 16, N_, B_ * 2), dim3(256), 0, stream>>>(Q, K, Qb, Kb);
        cvt_v_kernel<<<dim3(S_ / 64, N_, B_), dim3(256), 0, stream>>>(V, Vt);
        for (int b = 0; b < B_; ++b) {  // RD is single-batch; batches sequential
            den_kernel<<<dim3(S_ / 128, S_ / 32, 1), dim3(256), 0, stream>>>(Qb, Kb, M, RD, b);
            apply_kernel<<<dim3(S_ / 32, N_, 1), dim3(256), 0, stream>>>(Qb, Kb, Vt, RD, O, b);
        }
    } else {
        // fallback: R4 path (needs 24 MB)
        hipMemsetAsync(d_out, 0, (size_t)out_size * sizeof(float), stream);
        __bf16* Qb = (__bf16*)d_ws;
        __bf16* Kb = Qb + per;
        __bf16* Vt = Kb + per;
        cvt_qk_kernel<<<dim3(S_ / 16, N_, B_ * 2), dim3(256), 0, stream>>>(Q, K, Qb, Kb);
        cvt_v_kernel<<<dim3(S_ / 64, N_, B_), dim3(256), 0, stream>>>(V, Vt);
        sdpa_main_kernel<<<dim3(S_ / TQ, B_, KSPLIT), dim3(1024), 0, stream>>>(Qb, Kb, Vt, M, O);
    }
}

// Round 6
// 422.035 us; speedup vs baseline: 1.1016x; 1.1016x over previous
//
#include <hip/hip_runtime.h>
#include <hip/hip_bf16.h>

// Head-axis-softmax SDPA, B=2 S=2048 N=16 D=64, fp32 in/out.
// softmax over HEADS (n) -> local per (b,q,k). Two-pass, barrier-free:
//   den:   rd[q,k] = mask ? 1/sum_n exp(s_n/8) : NaN   (bf16, single batch, 8.4MB ws)
//   apply: per-head O += (exp(s/8)*rd) @ V, LDS C->A wave-local, atomic epilogue.
// R6 changes vs R5 (theory: shared ~16k cyc/iter wall = XCD L2 misses to L3):
//   * XCD-aware swizzle (blockIdx%8): den q-clustered; apply (headgroup,kq)-pinned
//     so K/V (~2MB) are L2-resident per XCD and RD streams once per XCD.
//   * rd multiplied in A-layout AFTER the LDS round trip: 2 coalesced b128
//     loads/iter instead of 16 scattered 64B loads.
//   * branchless K-tile / next-head prefetch to hide load latency.

#define B_ 2
#define S_ 2048
#define N_ 16
#define D_ 64
#define PK 40

typedef __bf16 bf16x4 __attribute__((ext_vector_type(4)));
typedef __bf16 bf16x8 __attribute__((ext_vector_type(8)));
typedef float  f32x16 __attribute__((ext_vector_type(16)));

// ---------------------------------------------------------------------------
// Pre-pass 1: Q,K [b,s,n,d] f32 -> [b,n,s,d] bf16.
// ---------------------------------------------------------------------------
__global__ __launch_bounds__(256) void cvt_qk_kernel(
    const float* __restrict__ Qf, const float* __restrict__ Kf,
    __bf16* __restrict__ Qb, __bf16* __restrict__ Kb)
{
    const int z = blockIdx.z;
    const float* src = (z < B_) ? Qf : Kf;
    __bf16*      dst = (z < B_) ? Qb : Kb;
    const int b = (z < B_) ? z : z - B_;
    const int n = blockIdx.y;
    const int t = threadIdx.x;
    const int d4 = (t & 15) * 4;
    const int s  = blockIdx.x * 16 + (t >> 4);

    const float4 v = *(const float4*)&src[(((size_t)b * S_ + s) * N_ + n) * D_ + d4];
    bf16x4 o;
    o[0] = (__bf16)v.x; o[1] = (__bf16)v.y; o[2] = (__bf16)v.z; o[3] = (__bf16)v.w;
    *(bf16x4*)&dst[(((size_t)b * N_ + n) * S_ + s) * D_ + d4] = o;
}

// ---------------------------------------------------------------------------
// Pre-pass 2: V [b,s,n,d] f32 -> [b,n,d,s] bf16 (transpose via LDS).
// ---------------------------------------------------------------------------
__global__ __launch_bounds__(256) void cvt_v_kernel(
    const float* __restrict__ V, __bf16* __restrict__ Vt)
{
    __shared__ __bf16 tile[64][68];
    const int s0 = blockIdx.x * 64;
    const int n  = blockIdx.y;
    const int b  = blockIdx.z;
    const int t  = threadIdx.x;

    {
        const int d4 = (t & 15) * 4;
        const int sr = t >> 4;
        #pragma unroll
        for (int r = 0; r < 4; ++r) {
            const int s = sr + r * 16;
            const float4 v = *(const float4*)&V[(((size_t)b * S_ + s0 + s) * N_ + n) * D_ + d4];
            tile[s][d4 + 0] = (__bf16)v.x;
            tile[s][d4 + 1] = (__bf16)v.y;
            tile[s][d4 + 2] = (__bf16)v.z;
            tile[s][d4 + 3] = (__bf16)v.w;
        }
    }
    __syncthreads();
    {
        const int s4 = (t & 15) * 4;
        const int dr = t >> 4;
        #pragma unroll
        for (int r = 0; r < 4; ++r) {
            const int d = dr + r * 16;
            bf16x4 o;
            o[0] = tile[s4 + 0][d];
            o[1] = tile[s4 + 1][d];
            o[2] = tile[s4 + 2][d];
            o[3] = tile[s4 + 3][d];
            *(bf16x4*)&Vt[(((size_t)b * N_ + n) * D_ + d) * S_ + s0 + s4] = o;
        }
    }
}

// ---------------------------------------------------------------------------
// den: one wave = 32x32 (q,k) tile, 16-head register-only cross-head sum.
// grid 1024 (1-D). Swizzle: xcd=L&7 gets q-blocks [xcd*8, xcd*8+8) -> Q
// (0.5 MB incl all heads) L2-resident per XCD; K streams.
// ---------------------------------------------------------------------------
__global__ __launch_bounds__(256) void den_kernel(
    const __bf16* __restrict__ Qb, const __bf16* __restrict__ Kb,
    const int* __restrict__ M, __bf16* __restrict__ RD, int b)
{
    const int tid  = threadIdx.x;
    const int w    = tid >> 6;
    const int lane = tid & 63;
    const int lo   = lane & 31;
    const int hi   = lane >> 5;

    const int L    = blockIdx.x;
    const int xcd  = L & 7;
    const int slot = L >> 3;                 // 0..127
    const int q0   = (xcd * 8 + (slot & 7)) * 32;
    const int k0   = (slot >> 3) * 128 + w * 32;

    const __bf16* Qp = Qb + (size_t)b * N_ * S_ * D_ + (size_t)(q0 + lo) * D_ + hi * 8;
    const __bf16* Kp = Kb + (size_t)b * N_ * S_ * D_ + (size_t)(k0 + lo) * D_ + hi * 8;

    bf16x8 qf[4], kf[4];
    #pragma unroll
    for (int c = 0; c < 4; ++c) {
        qf[c] = *(const bf16x8*)(Qp + c * 16);
        kf[c] = *(const bf16x8*)(Kp + c * 16);
    }

    f32x16 sum = {};
    for (int n = 0; n < N_; ++n) {
        f32x16 acc = {};
        #pragma unroll
        for (int c = 0; c < 4; ++c)
            acc = __builtin_amdgcn_mfma_f32_32x32x16_bf16(qf[c], kf[c], acc, 0, 0, 0);

        // branchless next-head prefetch (last iter harmlessly reloads head 15)
        const int n2 = (n + 1 < N_) ? (n + 1) : n;
        const __bf16* qh = Qp + (size_t)n2 * S_ * D_;
        const __bf16* kh = Kp + (size_t)n2 * S_ * D_;
        bf16x8 qn[4], kn[4];
        #pragma unroll
        for (int c = 0; c < 4; ++c) {
            qn[c] = *(const bf16x8*)(qh + c * 16);
            kn[c] = *(const bf16x8*)(kh + c * 16);
        }

        #pragma unroll
        for (int r = 0; r < 16; ++r) sum[r] += __expf(acc[r] * 0.125f);

        #pragma unroll
        for (int c = 0; c < 4; ++c) { qf[c] = qn[c]; kf[c] = kn[c]; }
    }

    #pragma unroll
    for (int r = 0; r < 16; ++r) {
        const int row = (r & 3) + 8 * (r >> 2) + 4 * hi;   // C layout
        const int m = M[(size_t)b * S_ * S_ + (size_t)(q0 + row) * S_ + (k0 + lo)];
        const float rd = m ? (1.0f / sum[r]) : __builtin_nanf("");
        RD[(size_t)(q0 + row) * S_ + (k0 + lo)] = (__bf16)rd;
    }
}

// ---------------------------------------------------------------------------
// apply: block = 4 waves = 4 heads (one head-group), one q-tile, one k-quarter.
// grid 1024 (1-D). Swizzle: xcd=L&7 -> (hg = xcd&3, kq-high = xcd>>2), so each
// XCD holds 4 heads x 2 k-quarters of K+V (~2 MB, L2-resident) and streams RD
// once (~4 MB), shared by the 4 heads via L1. No barriers anywhere.
// ---------------------------------------------------------------------------
__global__ __launch_bounds__(256) void apply_kernel(
    const __bf16* __restrict__ Qb, const __bf16* __restrict__ Kb,
    const __bf16* __restrict__ Vt, const __bf16* __restrict__ RD,
    float* __restrict__ O, int b)
{
    __shared__ __align__(16) __bf16 pw[4][32][PK];  // per-wave E tiles, 10 KB

    const int tid  = threadIdx.x;
    const int w    = tid >> 6;
    const int lane = tid & 63;
    const int lo   = lane & 31;
    const int hi   = lane >> 5;

    const int L    = blockIdx.x;
    const int xcd  = L & 7;
    const int slot = L >> 3;                  // 0..127
    const int hg   = xcd & 3;
    const int q0   = (slot & 63) * 32;
    const int kq   = (xcd >> 2) * 2 + (slot >> 6);   // 0..3
    const int n    = hg * 4 + w;
    const int kbase = kq * 512;

    const __bf16* Qh  = Qb + ((size_t)b * N_ + n) * S_ * D_;
    const __bf16* Kh  = Kb + ((size_t)b * N_ + n) * S_ * D_;
    const __bf16* Vh  = Vt + ((size_t)b * N_ + n) * D_ * S_;
    const __bf16* RDq = RD + (size_t)(q0 + lo) * S_;  // row base for A-layout rd

    bf16x8 qf[4];
    #pragma unroll
    for (int c = 0; c < 4; ++c)
        qf[c] = *(const bf16x8*)&Qh[(size_t)(q0 + lo) * D_ + c * 16 + hi * 8];

    f32x16 o0 = {}, o1 = {};

    bf16x8 kf[4];
    #pragma unroll
    for (int c = 0; c < 4; ++c)
        kf[c] = *(const bf16x8*)&Kh[(size_t)(kbase + lo) * D_ + c * 16 + hi * 8];

    for (int it = 0; it < 16; ++it) {
        const int k0 = kbase + it * 32;

        // QK^T on prefetched K tile
        f32x16 s = {};
        #pragma unroll
        for (int c = 0; c < 4; ++c)
            s = __builtin_amdgcn_mfma_f32_32x32x16_bf16(qf[c], kf[c], s, 0, 0, 0);

        // prefetch next K tile (branchless; last iter reloads current)
        const int k1 = kbase + ((it + 1 < 16) ? (it + 1) : it) * 32;
        bf16x8 kn[4];
        #pragma unroll
        for (int c = 0; c < 4; ++c)
            kn[c] = *(const bf16x8*)&Kh[(size_t)(k1 + lo) * D_ + c * 16 + hi * 8];

        // V B-frags + rd (A-layout, coalesced b128) — latency hidden under exp/LDS
        bf16x8 vf[2][2];
        #pragma unroll
        for (int ks = 0; ks < 2; ++ks)
            #pragma unroll
            for (int dt = 0; dt < 2; ++dt)
                vf[ks][dt] = *(const bf16x8*)&Vh[(size_t)(dt * 32 + lo) * S_
                                                 + k0 + ks * 16 + hi * 8];
        bf16x8 rdv[2];
        #pragma unroll
        for (int ks = 0; ks < 2; ++ks)
            rdv[ks] = *(const bf16x8*)&RDq[k0 + ks * 16 + hi * 8];

        // E = exp(s/8) -> wave-local LDS (C-layout scatter)
        #pragma unroll
        for (int r = 0; r < 16; ++r) {
            const int row = (r & 3) + 8 * (r >> 2) + 4 * hi;
            pw[w][row][lo] = (__bf16)__expf(s[r] * 0.125f);
        }

        // read back in A-layout, multiply by rd, PV MFMA (wave-local, no barrier)
        #pragma unroll
        for (int ks = 0; ks < 2; ++ks) {
            bf16x8 ef = *(const bf16x8*)&pw[w][lo][ks * 16 + hi * 8];
            bf16x8 wf;
            #pragma unroll
            for (int j = 0; j < 8; ++j)
                wf[j] = (__bf16)((float)ef[j] * (float)rdv[ks][j]);
            o0 = __builtin_amdgcn_mfma_f32_32x32x16_bf16(wf, vf[ks][0], o0, 0, 0, 0);
            o1 = __builtin_amdgcn_mfma_f32_32x32x16_bf16(wf, vf[ks][1], o1, 0, 0, 0);
        }

        #pragma unroll
        for (int c = 0; c < 4; ++c) kf[c] = kn[c];
    }

    // epilogue: 4 k-quarter blocks combine via device atomics (O pre-zeroed)
    #pragma unroll
    for (int r = 0; r < 16; ++r) {
        const int row = (r & 3) + 8 * (r >> 2) + 4 * hi;
        const size_t base = (((size_t)b * N_ + n) * S_ + (q0 + row)) * (size_t)D_;
        atomicAdd(&O[base + lo],      o0[r]);
        atomicAdd(&O[base + 32 + lo], o1[r]);
    }
}

// ---------------------------------------------------------------------------
// Fallback: R4 monolith (needs 24 MB ws).
// ---------------------------------------------------------------------------
#define TQ 32
#define TK 32
#define KSPLIT 4
#define ITERS (S_ / TK / KSPLIT)

__global__ __launch_bounds__(1024) void sdpa_main_kernel(
    const __bf16* __restrict__ Qb, const __bf16* __restrict__ Kb,
    const __bf16* __restrict__ Vt, const int* __restrict__ M,
    float* __restrict__ O)
{
    __shared__ __align__(16) __bf16 pbuf[N_][TQ][PK];

    const int tid  = threadIdx.x;
    const int n    = tid >> 6;
    const int lane = tid & 63;
    const int lo   = lane & 31;
    const int hi   = lane >> 5;

    const int q0 = blockIdx.x * TQ;
    const int b  = blockIdx.y;
    const int kz = blockIdx.z;

    const __bf16* Qh = Qb + ((size_t)b * N_ + n) * S_ * D_;
    const __bf16* Kh = Kb + ((size_t)b * N_ + n) * S_ * D_;
    const __bf16* Vh = Vt + ((size_t)b * N_ + n) * D_ * S_;

    bf16x8 qf[4];
    #pragma unroll
    for (int ks = 0; ks < 4; ++ks)
        qf[ks] = *(const bf16x8*)&Qh[(size_t)(q0 + lo) * D_ + ks * 16 + hi * 8];

    f32x16 o0 = {};
    f32x16 o1 = {};

    for (int it = 0; it < ITERS; ++it) {
        const int k0 = (kz * ITERS + it) * TK;

        f32x16 s = {};
        #pragma unroll
        for (int ks = 0; ks < 4; ++ks) {
            bf16x8 kf = *(const bf16x8*)&Kh[(size_t)(k0 + lo) * D_ + ks * 16 + hi * 8];
            s = __builtin_amdgcn_mfma_f32_32x32x16_bf16(qf[ks], kf, s, 0, 0, 0);
        }

        bf16x8 vf[2][2];
        #pragma unroll
        for (int kstep = 0; kstep < 2; ++kstep)
            #pragma unroll
            for (int dt = 0; dt < 2; ++dt)
                vf[kstep][dt] = *(const bf16x8*)&Vh[(size_t)(dt * 32 + lo) * S_
                                                   + k0 + kstep * 16 + hi * 8];

        #pragma unroll
        for (int r = 0; r < 16; ++r) {
            const int row = (r & 3) + 8 * (r >> 2) + 4 * hi;
            pbuf[n][row][lo] = (__bf16)__expf(s[r] * 0.125f);
        }

        __syncthreads();

        {
            const int tq = tid >> 5;
            const int tk = tid & 31;
            const int m = M[(size_t)b * S_ * S_ + (size_t)(q0 + tq) * S_ + (k0 + tk)];
            float pv[16];
            float sum = 0.f;
            #pragma unroll
            for (int j = 0; j < 16; ++j) { pv[j] = (float)pbuf[j][tq][tk]; sum += pv[j]; }
            const float rd = m ? (1.0f / sum) : __builtin_nanf("");
            #pragma unroll
            for (int j = 0; j < 16; ++j) pbuf[j][tq][tk] = (__bf16)(pv[j] * rd);
        }

        __syncthreads();

        #pragma unroll
        for (int kstep = 0; kstep < 2; ++kstep) {
            bf16x8 wf = *(const bf16x8*)&pbuf[n][lo][kstep * 16 + hi * 8];
            o0 = __builtin_amdgcn_mfma_f32_32x32x16_bf16(wf, vf[kstep][0], o0, 0, 0, 0);
            o1 = __builtin_amdgcn_mfma_f32_32x32x16_bf16(wf, vf[kstep][1], o1, 0, 0, 0);
        }

        __syncthreads();
    }

    #pragma unroll
    for (int r = 0; r < 16; ++r) {
        const int row = (r & 3) + 8 * (r >> 2) + 4 * hi;
        const size_t base = (((size_t)b * N_ + n) * S_ + (q0 + row)) * (size_t)D_;
        atomicAdd(&O[base + lo],      o0[r]);
        atomicAdd(&O[base + 32 + lo], o1[r]);
    }
}

extern "C" void kernel_launch(void* const* d_in, const int* in_sizes, int n_in,
                              void* d_out, int out_size, void* d_ws, size_t ws_size,
                              hipStream_t stream) {
    const float* Q = (const float*)d_in[0];
    const float* K = (const float*)d_in[1];
    const float* V = (const float*)d_in[2];
    const int*   M = (const int*)d_in[3];
    float* O = (float*)d_out;

    hipMemsetAsync(d_out, 0, (size_t)out_size * sizeof(float), stream);

    const size_t per  = (size_t)B_ * N_ * S_ * D_;                 // 4.19 M elems
    const size_t need = (3 * per + (size_t)S_ * S_) * sizeof(__bf16);  // 32.9 MB

    __bf16* Qb = (__bf16*)d_ws;
    __bf16* Kb = Qb + per;
    __bf16* Vt = Kb + per;

    cvt_qk_kernel<<<dim3(S_ / 16, N_, B_ * 2), dim3(256), 0, stream>>>(Q, K, Qb, Kb);
    cvt_v_kernel<<<dim3(S_ / 64, N_, B_), dim3(256), 0, stream>>>(V, Vt);

    if (ws_size >= need) {
        __bf16* RD = Vt + per;   // single-batch rd, reused (stream-serialized)
        for (int b = 0; b < B_; ++b) {
            den_kernel<<<dim3(1024), dim3(256), 0, stream>>>(Qb, Kb, M, RD, b);
            apply_kernel<<<dim3(1024), dim3(256), 0, stream>>>(Qb, Kb, Vt, RD, O, b);
        }
    } else {
        sdpa_main_kernel<<<dim3(S_ / TQ, B_, KSPLIT), dim3(1024), 0, stream>>>(Qb, Kb, Vt, M, O);
    }
}